// Round 5
// baseline (749.253 us; speedup 1.0000x reference)
//
#include <hip/hip_runtime.h>

typedef _Float16 h4 __attribute__((ext_vector_type(4)));
typedef float    f4 __attribute__((ext_vector_type(4)));

#define N_B   128
#define N_IN  1152
#define ICH   16                 // i-tiles per block
#define NCH   (N_IN / ICH)       // 72 chunks
#define BSPL  16
#define BCH   (N_B / BSPL)       // 8 b per block
#define STILE 4                  // tiles per LDS stage (one per wave)
#define NSTG  4                  // stages per block
#define WPITCH 33                // pitch (floats) for conflict-free lane fragments

// workspace: Spart [NCH][N_B][256] f32 = 9.44 MB, then Vsum (128 KB). 9.57 MB proven safe.
#define SPART_SZ ((size_t)NCH * N_B * 256 * 4)

// sblk slot (bb, t*64+lane):
//   route0 (A-layout): holds s[o=lane&15, d=(lane>>4)*4+t]
//   route  (D-layout): holds s[o=(lane>>4)*4+t, d=lane&15]
// both give redsq permutation q = t*64 + (x>>2)*16 + y.

// Cooperative W-tile fill: global contiguous -> WL[tl][chunk ll][33-pitch]
// lane fragment = Wg[ll*32 .. +31] with ll = lo*4+hi.
#define FILL_WL(tl_)                                                         \
    {                                                                        \
        const float* wg = W + (size_t)(c * ICH + stg * STILE + (tl_)) * 2048;\
        int g = tid * 4;                                                     \
        f4 a = *(const f4*)(wg + g);                                         \
        WL[tl_][g >> 5][(g & 31) + 0] = a[0];                                \
        WL[tl_][g >> 5][(g & 31) + 1] = a[1];                                \
        WL[tl_][g >> 5][(g & 31) + 2] = a[2];                                \
        WL[tl_][g >> 5][(g & 31) + 3] = a[3];                                \
        int g2 = g + 1024;                                                   \
        f4 b2 = *(const f4*)(wg + g2);                                       \
        WL[tl_][g2 >> 5][(g2 & 31) + 0] = b2[0];                             \
        WL[tl_][g2 >> 5][(g2 & 31) + 1] = b2[1];                             \
        WL[tl_][g2 >> 5][(g2 & 31) + 2] = b2[2];                             \
        WL[tl_][g2 >> 5][(g2 & 31) + 3] = b2[3];                             \
    }

// Gather this wave's fragment (tile = w) from LDS into named f4 regs + fence.
#define GATHER_W()                                                           \
    const float* fl = &WL[w][ll][0];                                         \
    f4 w0, w1, w2, w3, w4, w5, w6, w7;                                       \
    { w0[0]=fl[0];  w0[1]=fl[1];  w0[2]=fl[2];  w0[3]=fl[3];                 \
      w1[0]=fl[4];  w1[1]=fl[5];  w1[2]=fl[6];  w1[3]=fl[7];                 \
      w2[0]=fl[8];  w2[1]=fl[9];  w2[2]=fl[10]; w2[3]=fl[11];                \
      w3[0]=fl[12]; w3[1]=fl[13]; w3[2]=fl[14]; w3[3]=fl[15];                \
      w4[0]=fl[16]; w4[1]=fl[17]; w4[2]=fl[18]; w4[3]=fl[19];                \
      w5[0]=fl[20]; w5[1]=fl[21]; w5[2]=fl[22]; w5[3]=fl[23];                \
      w6[0]=fl[24]; w6[1]=fl[25]; w6[2]=fl[26]; w6[3]=fl[27];                \
      w7[0]=fl[28]; w7[1]=fl[29]; w7[2]=fl[30]; w7[3]=fl[31]; }              \
    asm volatile("" : "+v"(w0), "+v"(w1), "+v"(w2), "+v"(w3),                \
                      "+v"(w4), "+v"(w5), "+v"(w6), "+v"(w7));

#define UHAT(u0_, u1_, u2_, u3_, xa_, xb_)                                   \
    float u0_ = fmaf(w0[0], xa_[0], fmaf(w0[1], xa_[1], fmaf(w0[2], xa_[2],  \
                fmaf(w0[3], xa_[3], fmaf(w1[0], xb_[0], fmaf(w1[1], xb_[1],  \
                fmaf(w1[2], xb_[2], w1[3] * xb_[3])))))));                   \
    float u1_ = fmaf(w2[0], xa_[0], fmaf(w2[1], xa_[1], fmaf(w2[2], xa_[2],  \
                fmaf(w2[3], xa_[3], fmaf(w3[0], xb_[0], fmaf(w3[1], xb_[1],  \
                fmaf(w3[2], xb_[2], w3[3] * xb_[3])))))));                   \
    float u2_ = fmaf(w4[0], xa_[0], fmaf(w4[1], xa_[1], fmaf(w4[2], xa_[2],  \
                fmaf(w4[3], xa_[3], fmaf(w5[0], xb_[0], fmaf(w5[1], xb_[1],  \
                fmaf(w5[2], xb_[2], w5[3] * xb_[3])))))));                   \
    float u3_ = fmaf(w6[0], xa_[0], fmaf(w6[1], xa_[1], fmaf(w6[2], xa_[2],  \
                fmaf(w6[3], xa_[3], fmaf(w7[0], xb_[0], fmaf(w7[1], xb_[1],  \
                fmaf(w7[2], xb_[2], w7[3] * xb_[3])))))));

// ---------------------------------------------------------------------------
// iter 0: c uniform = 1/16.
// ---------------------------------------------------------------------------
__global__ __launch_bounds__(256, 3) void k_route0(const float* __restrict__ x,
                                                   const float* __restrict__ W,
                                                   float* __restrict__ Spart) {
    __shared__ float WL[STILE][64][WPITCH];   // 33792 B
    __shared__ float xsh[BCH][ICH][8];        // 4096 B
    __shared__ float sblk[BCH * 256];         // 8192 B
    const int c = blockIdx.x, spl = blockIdx.y;
    const int b0 = spl * BCH;
    const int tid = threadIdx.x, w = tid >> 6, lane = tid & 63;
    const int lo = lane & 15, hi = lane >> 4, ll = lo * 4 + hi;

    {   // stage x (coalesced)
        int bb = tid >> 5, r = tid & 31, ii = r >> 1, k4 = (r & 1) * 4;
        *(f4*)&xsh[bb][ii][k4] =
            *(const f4*)(x + ((size_t)(b0 + bb) * N_IN + c * ICH + ii) * 8 + k4);
    }
#pragma unroll
    for (int r = 0; r < BCH; r++) sblk[r * 256 + tid] = 0.f;

    for (int stg = 0; stg < NSTG; stg++) {
        __syncthreads();            // prev compute done before WL overwrite
        FILL_WL(0) FILL_WL(1) FILL_WL(2) FILL_WL(3)
        __syncthreads();            // fill visible
        const int iloc = stg * STILE + w;
        GATHER_W()
#define R0_BB(bb)                                                            \
        {                                                                    \
            f4 xa = *(const f4*)&xsh[bb][iloc][0];                           \
            f4 xb = *(const f4*)&xsh[bb][iloc][4];                           \
            UHAT(u0, u1, u2, u3, xa, xb)                                     \
            atomicAdd(&sblk[bb * 256 + 0 * 64 + lane], u0 * 0.0625f);        \
            atomicAdd(&sblk[bb * 256 + 1 * 64 + lane], u1 * 0.0625f);        \
            atomicAdd(&sblk[bb * 256 + 2 * 64 + lane], u2 * 0.0625f);        \
            atomicAdd(&sblk[bb * 256 + 3 * 64 + lane], u3 * 0.0625f);        \
        }
        R0_BB(0) R0_BB(1) R0_BB(2) R0_BB(3) R0_BB(4) R0_BB(5) R0_BB(6) R0_BB(7)
    }
    __syncthreads();
    {   // coalesced Spart store: rows b0..b0+7 are contiguous
        f4* dst = (f4*)(Spart + ((size_t)c * N_B + b0) * 256);
        const f4* src = (const f4*)sblk;
        dst[tid] = src[tid];
        dst[tid + 256] = src[tid + 256];
    }
}

// ---------------------------------------------------------------------------
// iter >= 1: u_hat (fp32, fragments from LDS), logits via split-f16 MFMA vs
// named-register Vsum fragments, softmax over o, accumulate c*u.
// ---------------------------------------------------------------------------
__global__ __launch_bounds__(256, 3) void k_route(const float* __restrict__ x,
                                                  const float* __restrict__ W,
                                                  const float* __restrict__ Vsum,
                                                  float* __restrict__ Spart) {
    __shared__ float WL[STILE][64][WPITCH];
    __shared__ float xsh[BCH][ICH][8];
    __shared__ float sblk[BCH * 256];
    const int c = blockIdx.x, spl = blockIdx.y;
    const int b0 = spl * BCH;
    const int tid = threadIdx.x, w = tid >> 6, lane = tid & 63;
    const int lo = lane & 15, hi = lane >> 4, ll = lo * 4 + hi;

    {
        int bb = tid >> 5, r = tid & 31, ii = r >> 1, k4 = (r & 1) * 4;
        *(f4*)&xsh[bb][ii][k4] =
            *(const f4*)(x + ((size_t)(b0 + bb) * N_IN + c * ICH + ii) * 8 + k4);
    }
#pragma unroll
    for (int r = 0; r < BCH; r++) sblk[r * 256 + tid] = 0.f;

    // Vsum B-fragments, named registers (coalesced f4 loads)
    h4 vh0, vh1, vh2, vh3, vh4, vh5, vh6, vh7;
    h4 vl0, vl1, vl2, vl3, vl4, vl5, vl6, vl7;
#define LOAD_V(bb)                                                           \
    {                                                                        \
        f4 vv = *(const f4*)(Vsum + ((size_t)(b0 + bb) * 256 + lo * 16 + hi * 4)); \
        _Float16 h0 = (_Float16)vv[0], h1 = (_Float16)vv[1];                 \
        _Float16 h2 = (_Float16)vv[2], h3 = (_Float16)vv[3];                 \
        vh##bb[0] = h0; vh##bb[1] = h1; vh##bb[2] = h2; vh##bb[3] = h3;      \
        vl##bb[0] = (_Float16)(vv[0] - (float)h0);                           \
        vl##bb[1] = (_Float16)(vv[1] - (float)h1);                           \
        vl##bb[2] = (_Float16)(vv[2] - (float)h2);                           \
        vl##bb[3] = (_Float16)(vv[3] - (float)h3);                           \
    }
    LOAD_V(0) LOAD_V(1) LOAD_V(2) LOAD_V(3) LOAD_V(4) LOAD_V(5) LOAD_V(6) LOAD_V(7)

    // identity B-fragment (U -> D-layout transpose MFMA)
    h4 idf;
#pragma unroll
    for (int t = 0; t < 4; t++) idf[t] = (_Float16)((hi * 4 + t == lo) ? 1.f : 0.f);

    for (int stg = 0; stg < NSTG; stg++) {
        __syncthreads();
        FILL_WL(0) FILL_WL(1) FILL_WL(2) FILL_WL(3)
        __syncthreads();
        const int iloc = stg * STILE + w;
        GATHER_W()
#define R_BB(bb)                                                             \
        {                                                                    \
            f4 xa = *(const f4*)&xsh[bb][iloc][0];                           \
            f4 xb = *(const f4*)&xsh[bb][iloc][4];                           \
            UHAT(u0, u1, u2, u3, xa, xb)                                     \
            h4 uh, ul;                                                       \
            { _Float16 h0 = (_Float16)u0, h1 = (_Float16)u1;                 \
              _Float16 h2 = (_Float16)u2, h3 = (_Float16)u3;                 \
              uh[0] = h0; uh[1] = h1; uh[2] = h2; uh[3] = h3;                \
              ul[0] = (_Float16)(u0 - (float)h0);                            \
              ul[1] = (_Float16)(u1 - (float)h1);                            \
              ul[2] = (_Float16)(u2 - (float)h2);                            \
              ul[3] = (_Float16)(u3 - (float)h3); }                          \
            f4 z = {0.f, 0.f, 0.f, 0.f};                                     \
            f4 L = __builtin_amdgcn_mfma_f32_16x16x16f16(uh, vh##bb, z, 0, 0, 0); \
            L = __builtin_amdgcn_mfma_f32_16x16x16f16(ul, vh##bb, L, 0, 0, 0);    \
            L = __builtin_amdgcn_mfma_f32_16x16x16f16(uh, vl##bb, L, 0, 0, 0);    \
            f4 ud = __builtin_amdgcn_mfma_f32_16x16x16f16(uh, idf, z, 0, 0, 0);   \
            ud = __builtin_amdgcn_mfma_f32_16x16x16f16(ul, idf, ud, 0, 0, 0);     \
            float p0 = __expf(L[0]), p1 = __expf(L[1]);                      \
            float p2 = __expf(L[2]), p3 = __expf(L[3]);                      \
            float zs = (p0 + p1) + (p2 + p3);                                \
            zs += __shfl_xor(zs, 16);                                        \
            zs += __shfl_xor(zs, 32);                                        \
            float rin = __builtin_amdgcn_rcpf(zs);                           \
            atomicAdd(&sblk[bb * 256 + 0 * 64 + lane], p0 * rin * ud[0]);    \
            atomicAdd(&sblk[bb * 256 + 1 * 64 + lane], p1 * rin * ud[1]);    \
            atomicAdd(&sblk[bb * 256 + 2 * 64 + lane], p2 * rin * ud[2]);    \
            atomicAdd(&sblk[bb * 256 + 3 * 64 + lane], p3 * rin * ud[3]);    \
        }
        R_BB(0) R_BB(1) R_BB(2) R_BB(3) R_BB(4) R_BB(5) R_BB(6) R_BB(7)
    }
    __syncthreads();
    {
        f4* dst = (f4*)(Spart + ((size_t)c * N_B + b0) * 256);
        const f4* src = (const f4*)sblk;
        dst[tid] = src[tid];
        dst[tid + 256] = src[tid + 256];
    }
}

// ---------------------------------------------------------------------------
// Reduce 72 chunks (undo lane-major permutation) + squash. 1024 threads:
// 4-way split of the cc-sum for latency hiding, LDS reduce, wave-0 squashes.
// MODE 0: Vsum = v ; MODE 1: Vsum += v ; MODE 2: out = v
// ---------------------------------------------------------------------------
template <int MODE>
__global__ __launch_bounds__(1024) void k_redsq(const float* __restrict__ Spart,
                                                float* __restrict__ Vsum,
                                                float* __restrict__ out) {
    __shared__ float red[4][256];
    const int b = blockIdx.x, tid = threadIdx.x;
    const int p = tid >> 8, t8 = tid & 255;
    const int o = t8 >> 4, d = t8 & 15;
    const int q = (MODE == 0) ? ((d & 3) * 64 + (d >> 2) * 16 + o)
                              : ((o & 3) * 64 + (o >> 2) * 16 + d);
    float s = 0.f;
#pragma unroll 6
    for (int cc = p * (NCH / 4); cc < (p + 1) * (NCH / 4); cc++)
        s += Spart[((size_t)cc * N_B + b) * 256 + q];
    red[p][t8] = s;
    __syncthreads();
    if (p == 0) {
        s = (red[0][t8] + red[1][t8]) + (red[2][t8] + red[3][t8]);
        float sq = s * s;
        sq += __shfl_xor(sq, 1);
        sq += __shfl_xor(sq, 2);
        sq += __shfl_xor(sq, 4);
        sq += __shfl_xor(sq, 8);
        float scale = sq * __builtin_amdgcn_rcpf(1.f + sq);
        float v = s * scale * __builtin_amdgcn_rsqf(sq + 1e-8f);
        size_t idx = (size_t)b * 256 + t8;
        if (MODE == 0)      Vsum[idx] = v;
        else if (MODE == 1) Vsum[idx] += v;
        else                out[idx] = v;
    }
}

// ---------------------------------------------------------------------------
extern "C" void kernel_launch(void* const* d_in, const int* in_sizes, int n_in,
                              void* d_out, int out_size, void* d_ws, size_t ws_size,
                              hipStream_t stream) {
    (void)in_sizes; (void)n_in; (void)out_size; (void)ws_size;
    const float* x = (const float*)d_in[0];
    const float* W = (const float*)d_in[1];
    float* out   = (float*)d_out;
    float* Spart = (float*)d_ws;
    float* Vsum  = (float*)((char*)d_ws + SPART_SZ);

    dim3 rg(NCH, BSPL);
    k_route0<<<rg, 256, 0, stream>>>(x, W, Spart);
    k_redsq<0><<<N_B, 1024, 0, stream>>>(Spart, Vsum, out);
    k_route<<<rg, 256, 0, stream>>>(x, W, Vsum, Spart);
    k_redsq<1><<<N_B, 1024, 0, stream>>>(Spart, Vsum, out);
    k_route<<<rg, 256, 0, stream>>>(x, W, Vsum, Spart);
    k_redsq<2><<<N_B, 1024, 0, stream>>>(Spart, Vsum, out);
}

// Round 7
// 381.816 us; speedup vs baseline: 1.9623x; 1.9623x over previous
//
#include <hip/hip_runtime.h>

typedef _Float16 h4 __attribute__((ext_vector_type(4)));
typedef float    f4 __attribute__((ext_vector_type(4)));

#define N_B   128
#define N_IN  1152
#define ICH   16                 // i-tiles per block (4 waves x 2 stages x 2 tiles)
#define NCH   (N_IN / ICH)       // 72 chunks
#define BSPL  32
#define BCH   (N_B / BSPL)       // 4 b per block

// workspace: Spart [NCH][N_B][256] f32 = 9.44 MB + Vsum (128 KB). Proven safe.
#define SPART_SZ ((size_t)NCH * N_B * 256 * 4)

// sblk slot (bb, t*64+lane):
//   route0 (A-layout): holds s[o=lane&15, d=(lane>>4)*4+t]
//   route  (D-layout): holds s[o=(lane>>4)*4+t, d=lane&15]
// redsq permutation q = t*64 + (x>>2)*16 + y  (verified rounds 3-5).

#define DOT8(wa, wb, xa_, xb_)                                                    \
    fmaf(wa[0], xa_[0], fmaf(wa[1], xa_[1], fmaf(wa[2], xa_[2], fmaf(wa[3], xa_[3], \
    fmaf(wb[0], xb_[0], fmaf(wb[1], xb_[1], fmaf(wb[2], xb_[2], wb[3] * xb_[3])))))))

// 8 f4 of W for one tile into named regs: rows (o=lo, j=hi*4..hi*4+3), k 0..7
#define LOAD_W(P, i_)                                                             \
    f4 P##0, P##1, P##2, P##3, P##4, P##5, P##6, P##7;                            \
    {                                                                             \
        const f4* wp = (const f4*)(W + (size_t)(((i_) * 16 + lo) * 16 + hi * 4) * 8); \
        P##0 = wp[0]; P##1 = wp[1]; P##2 = wp[2]; P##3 = wp[3];                   \
        P##4 = wp[4]; P##5 = wp[5]; P##6 = wp[6]; P##7 = wp[7];                   \
    }

// u_hat fragment for one tile (4 fp32 values at (o=lo, d=hi*4+t))
#define TILE_U(P, W_, i_)                                                         \
    f4 P##xa, P##xb;                                                              \
    {                                                                             \
        const f4* xp = (const f4*)(x + ((size_t)b * N_IN + (i_)) * 8);            \
        P##xa = xp[0]; P##xb = xp[1];                                             \
    }                                                                             \
    float P##u0 = DOT8(W_##0, W_##1, P##xa, P##xb);                               \
    float P##u1 = DOT8(W_##2, W_##3, P##xa, P##xb);                               \
    float P##u2 = DOT8(W_##4, W_##5, P##xa, P##xb);                               \
    float P##u3 = DOT8(W_##6, W_##7, P##xa, P##xb);

// full routing chain for one tile: split-f16 MFMA logits + transpose + softmax
#define TILE_ROUTE(P, W_, i_)                                                     \
    TILE_U(P, W_, i_)                                                             \
    h4 P##uh, P##ul;                                                              \
    {                                                                             \
        _Float16 c0 = (_Float16)P##u0, c1 = (_Float16)P##u1;                      \
        _Float16 c2 = (_Float16)P##u2, c3 = (_Float16)P##u3;                      \
        P##uh[0] = c0; P##uh[1] = c1; P##uh[2] = c2; P##uh[3] = c3;               \
        P##ul[0] = (_Float16)(P##u0 - (float)c0);                                 \
        P##ul[1] = (_Float16)(P##u1 - (float)c1);                                 \
        P##ul[2] = (_Float16)(P##u2 - (float)c2);                                 \
        P##ul[3] = (_Float16)(P##u3 - (float)c3);                                 \
    }                                                                             \
    f4 P##L, P##ud;                                                               \
    {                                                                             \
        f4 z = {0.f, 0.f, 0.f, 0.f};                                              \
        P##L  = __builtin_amdgcn_mfma_f32_16x16x16f16(P##uh, vh, z, 0, 0, 0);     \
        P##L  = __builtin_amdgcn_mfma_f32_16x16x16f16(P##ul, vh, P##L, 0, 0, 0);  \
        P##L  = __builtin_amdgcn_mfma_f32_16x16x16f16(P##uh, vl, P##L, 0, 0, 0);  \
        P##ud = __builtin_amdgcn_mfma_f32_16x16x16f16(P##uh, idf, z, 0, 0, 0);    \
        P##ud = __builtin_amdgcn_mfma_f32_16x16x16f16(P##ul, idf, P##ud, 0, 0, 0);\
    }                                                                             \
    float P##p0 = __expf(P##L[0]), P##p1 = __expf(P##L[1]);                       \
    float P##p2 = __expf(P##L[2]), P##p3 = __expf(P##L[3]);                       \
    float P##zs = (P##p0 + P##p1) + (P##p2 + P##p3);                              \
    P##zs += __shfl_xor(P##zs, 16);                                               \
    P##zs += __shfl_xor(P##zs, 32);                                               \
    float P##rin = __builtin_amdgcn_rcpf(P##zs);

// ---------------------------------------------------------------------------
// iter 0: c uniform = 1/16.
// ---------------------------------------------------------------------------
__global__ __launch_bounds__(256, 3) void k_route0(const float* __restrict__ x,
                                                   const float* __restrict__ W,
                                                   float* __restrict__ Spart) {
    __shared__ float sblk[BCH * 256];   // 4 KB
    const int c = blockIdx.x, spl = blockIdx.y;
    const int b0 = spl * BCH;
    const int tid = threadIdx.x, w = tid >> 6, lane = tid & 63;
    const int lo = lane & 15, hi = lane >> 4;

    sblk[tid] = 0.f;
    sblk[tid + 256] = 0.f;
    sblk[tid + 512] = 0.f;
    sblk[tid + 768] = 0.f;
    __syncthreads();

#pragma unroll 1
    for (int stg = 0; stg < 2; stg++) {
        const int ib = c * ICH + stg * 8 + w * 2;
        LOAD_W(Wa, ib)
        LOAD_W(Wb, ib + 1)
#pragma unroll 1
        for (int bb = 0; bb < BCH; bb++) {
            const int b = b0 + bb;
            TILE_U(A, Wa, ib)
            TILE_U(B, Wb, ib + 1)
            atomicAdd(&sblk[bb * 256 + 0 * 64 + lane], (Au0 + Bu0) * 0.0625f);
            atomicAdd(&sblk[bb * 256 + 1 * 64 + lane], (Au1 + Bu1) * 0.0625f);
            atomicAdd(&sblk[bb * 256 + 2 * 64 + lane], (Au2 + Bu2) * 0.0625f);
            atomicAdd(&sblk[bb * 256 + 3 * 64 + lane], (Au3 + Bu3) * 0.0625f);
        }
    }
    __syncthreads();
    {   // coalesced: rows b0..b0+3 contiguous, 1024 floats = 256 f4
        f4* dst = (f4*)(Spart + ((size_t)c * N_B + b0) * 256);
        dst[tid] = ((const f4*)sblk)[tid];
    }
}

// ---------------------------------------------------------------------------
// iter >= 1: u_hat recompute + split-f16 MFMA logits vs Vsum + softmax + c*u.
// 2-tile explicit ILP; bb/stage loops pinned to no-unroll to bound pressure.
// ---------------------------------------------------------------------------
__global__ __launch_bounds__(256, 3) void k_route(const float* __restrict__ x,
                                                  const float* __restrict__ W,
                                                  const float* __restrict__ Vsum,
                                                  float* __restrict__ Spart) {
    __shared__ float sblk[BCH * 256];
    const int c = blockIdx.x, spl = blockIdx.y;
    const int b0 = spl * BCH;
    const int tid = threadIdx.x, w = tid >> 6, lane = tid & 63;
    const int lo = lane & 15, hi = lane >> 4;

    sblk[tid] = 0.f;
    sblk[tid + 256] = 0.f;
    sblk[tid + 512] = 0.f;
    sblk[tid + 768] = 0.f;

    h4 idf;   // identity B-fragment (U -> D-layout transpose MFMA)
#pragma unroll
    for (int t = 0; t < 4; t++) idf[t] = (_Float16)((hi * 4 + t == lo) ? 1.f : 0.f);
    __syncthreads();

#pragma unroll 1
    for (int stg = 0; stg < 2; stg++) {
        const int ib = c * ICH + stg * 8 + w * 2;
        LOAD_W(Wa, ib)
        LOAD_W(Wb, ib + 1)
#pragma unroll 1
        for (int bb = 0; bb < BCH; bb++) {
            const int b = b0 + bb;
            // Vsum B-fragment: lane (lo,hi) <- Vsum[b][lo*16 + hi*4 .. +3]
            f4 vv = *(const f4*)(Vsum + ((size_t)b * 256 + lo * 16 + hi * 4));
            h4 vh, vl;
            {
                _Float16 c0 = (_Float16)vv[0], c1 = (_Float16)vv[1];
                _Float16 c2 = (_Float16)vv[2], c3 = (_Float16)vv[3];
                vh[0] = c0; vh[1] = c1; vh[2] = c2; vh[3] = c3;
                vl[0] = (_Float16)(vv[0] - (float)c0);
                vl[1] = (_Float16)(vv[1] - (float)c1);
                vl[2] = (_Float16)(vv[2] - (float)c2);
                vl[3] = (_Float16)(vv[3] - (float)c3);
            }
            TILE_ROUTE(A, Wa, ib)
            TILE_ROUTE(B, Wb, ib + 1)
            atomicAdd(&sblk[bb * 256 + 0 * 64 + lane], Ap0 * Arin * Aud[0] + Bp0 * Brin * Bud[0]);
            atomicAdd(&sblk[bb * 256 + 1 * 64 + lane], Ap1 * Arin * Aud[1] + Bp1 * Brin * Bud[1]);
            atomicAdd(&sblk[bb * 256 + 2 * 64 + lane], Ap2 * Arin * Aud[2] + Bp2 * Brin * Bud[2]);
            atomicAdd(&sblk[bb * 256 + 3 * 64 + lane], Ap3 * Arin * Aud[3] + Bp3 * Brin * Bud[3]);
        }
    }
    __syncthreads();
    {
        f4* dst = (f4*)(Spart + ((size_t)c * N_B + b0) * 256);
        dst[tid] = ((const f4*)sblk)[tid];
    }
}

// ---------------------------------------------------------------------------
// Reduce 72 chunks (undo lane-major permutation) + squash. 1024 threads.
// MODE 0: Vsum = v ; MODE 1: Vsum += v ; MODE 2: out = v
// ---------------------------------------------------------------------------
template <int MODE>
__global__ __launch_bounds__(1024) void k_redsq(const float* __restrict__ Spart,
                                                float* __restrict__ Vsum,
                                                float* __restrict__ out) {
    __shared__ float red[4][256];
    const int b = blockIdx.x, tid = threadIdx.x;
    const int p = tid >> 8, t8 = tid & 255;
    const int o = t8 >> 4, d = t8 & 15;
    const int q = (MODE == 0) ? ((d & 3) * 64 + (d >> 2) * 16 + o)
                              : ((o & 3) * 64 + (o >> 2) * 16 + d);
    float s = 0.f;
#pragma unroll 6
    for (int cc = p * (NCH / 4); cc < (p + 1) * (NCH / 4); cc++)
        s += Spart[((size_t)cc * N_B + b) * 256 + q];
    red[p][t8] = s;
    __syncthreads();
    if (p == 0) {
        s = (red[0][t8] + red[1][t8]) + (red[2][t8] + red[3][t8]);
        float sq = s * s;
        sq += __shfl_xor(sq, 1);
        sq += __shfl_xor(sq, 2);
        sq += __shfl_xor(sq, 4);
        sq += __shfl_xor(sq, 8);
        float scale = sq * __builtin_amdgcn_rcpf(1.f + sq);
        float v = s * scale * __builtin_amdgcn_rsqf(sq + 1e-8f);
        size_t idx = (size_t)b * 256 + t8;
        if (MODE == 0)      Vsum[idx] = v;
        else if (MODE == 1) Vsum[idx] += v;
        else                out[idx] = v;
    }
}

// ---------------------------------------------------------------------------
extern "C" void kernel_launch(void* const* d_in, const int* in_sizes, int n_in,
                              void* d_out, int out_size, void* d_ws, size_t ws_size,
                              hipStream_t stream) {
    (void)in_sizes; (void)n_in; (void)out_size; (void)ws_size;
    const float* x = (const float*)d_in[0];
    const float* W = (const float*)d_in[1];
    float* out   = (float*)d_out;
    float* Spart = (float*)d_ws;
    float* Vsum  = (float*)((char*)d_ws + SPART_SZ);

    dim3 rg(NCH, BSPL);
    k_route0<<<rg, 256, 0, stream>>>(x, W, Spart);
    k_redsq<0><<<N_B, 1024, 0, stream>>>(Spart, Vsum, out);
    k_route<<<rg, 256, 0, stream>>>(x, W, Vsum, Spart);
    k_redsq<1><<<N_B, 1024, 0, stream>>>(Spart, Vsum, out);
    k_route<<<rg, 256, 0, stream>>>(x, W, Vsum, Spart);
    k_redsq<2><<<N_B, 1024, 0, stream>>>(Spart, Vsum, out);
}